// Round 14
// baseline (162.325 us; speedup 1.0000x reference)
//
#include <hip/hip_runtime.h>
#include <hip/hip_bf16.h>
#include <math.h>

#define E_EDGES 1000000
#define N_NODES 50000
#define N_C     64
#define N_REL   8
#define CHB     1024        // edges per block
#define CAP     224         // per-rel LDS capacity (mean 128, sigma 10.6 -> 9 sigma)
#define NBLK    977         // ceil(1e6 / 1024)

typedef __attribute__((ext_vector_type(4))) float floatx4;
typedef __attribute__((ext_vector_type(2))) float floatx2;

// pack 4 fp32 -> 4 fp8 e4m3 (RNE); byte j = element j
static __device__ __forceinline__ unsigned pk4_fp8(float a, float b, float c, float d) {
    unsigned w = 0;
    w = __builtin_amdgcn_cvt_pk_fp8_f32(a, b, w, false);
    w = __builtin_amdgcn_cvt_pk_fp8_f32(c, d, w, true);
    return w;
}

static __device__ __forceinline__ long long pack64(unsigned lo, unsigned hi) {
    uint2 u; u.x = lo; u.y = hi;
    return __builtin_bit_cast(long long, u);
}

// kappa slot permutation (verified R11/R12): Wp8 byte (q*16 + c*8 + j) of row
// holds fp8(W[row][(2c+(j>>2))*16 + 4q + (j&3)]); AS8 row byte q*16+u holds
// elem (u>>2)*16 + 4q + (u&3). One b128 per lane serves both the MFMA B-op
// and the src dot.
__global__ __launch_bounds__(256) void prep_kernel(
    const float* __restrict__ assign,
    const float* __restrict__ icl,
    const float* __restrict__ la,
    unsigned char* __restrict__ Wp8,
    unsigned char* __restrict__ AS8,
    float* __restrict__ out)
{
    int tid = blockIdx.x * blockDim.x + threadIdx.x;
    int nth = gridDim.x * blockDim.x;
    if (tid == 0) out[0] = 0.0f;

    // Wp8: one thread per output dword (512 rows x 16 dwords)
    for (int idx = tid; idx < N_REL * N_C * 16; idx += nth) {
        int row = idx >> 4, dq = idx & 15;
        int q = dq >> 2, c = (dq >> 1) & 1, jh = dq & 1;
        int k0 = (2 * c + jh) * 16 + 4 * q;   // bytes b=0..3 -> k = k0 + b
        float wv[4];
        #pragma unroll
        for (int b = 0; b < 4; ++b) {
            int srci = (row << 6) + k0 + b;
            float w = 1.0f / (1.0f + __expf(-icl[srci]));
            float g = 1.0f / (1.0f + __expf(-la[srci])) * 1.2f - 0.1f;
            g = fminf(fmaxf(g, 0.0f), 1.0f);
            wv[b] = w * g;
        }
        ((unsigned*)Wp8)[idx] = pk4_fp8(wv[0], wv[1], wv[2], wv[3]);
    }

    // AS8: one thread per node row; dword[q*4 + mt] = elems [16mt+4q, +4)
    for (int n = tid; n < N_NODES; n += nth) {
        const float4* a4 = (const float4*)(assign + (size_t)n * N_C);
        unsigned w[16];
        #pragma unroll
        for (int i = 0; i < 16; ++i) {
            float4 v = a4[i];
            w[i] = pk4_fp8(v.x, v.y, v.z, v.w);   // w[i] = elems 4i..4i+3
        }
        uint4* as = (uint4*)(AS8 + (size_t)n * N_C);
        #pragma unroll
        for (int q = 0; q < 4; ++q) {
            uint4 o;
            o.x = w[0 * 4 + q];
            o.y = w[1 * 4 + q];
            o.z = w[2 * 4 + q];
            o.w = w[3 * 4 + q];
            as[q] = o;
        }
    }
}

// Fused edge pass: bin CHB edges by relation in LDS, flatten to 16-edge
// groups, software-pipeline the group loop (prefetch next rec+S+D while
// computing current), native fp8 MFMA.
__global__ __launch_bounds__(256, 8) void edge_kernel(
    const unsigned char* __restrict__ AS8,
    const unsigned char* __restrict__ Wp8,
    const float* __restrict__ absent_bias,
    const int* __restrict__ ei, const int* __restrict__ et,
    const int* __restrict__ nei, const int* __restrict__ net,
    float* __restrict__ out)
{
    __shared__ unsigned list[N_REL * CAP];
    __shared__ unsigned cnt[N_REL];
    __shared__ unsigned glist[128];
    __shared__ int ng_s;
    __shared__ float red[4];
    if (threadIdx.x < N_REL) cnt[threadIdx.x] = 0u;
    __syncthreads();

    int blk = blockIdx.x;
    bool isneg = blk >= NBLK;
    int lb = isneg ? blk - NBLK : blk;
    const int* Es = isneg ? nei : ei;
    const int* Et = isneg ? net : et;
    float sign = isneg ? 1.0f : -1.0f;
    int base = lb * CHB;
    int elim = min(base + CHB, E_EDGES);

    for (int e = base + threadIdx.x; e < elim; e += 256) {
        int s = Es[e];
        int d = Es[E_EDGES + e];
        int r = Et[e];
        unsigned rank = atomicAdd(&cnt[r], 1u);
        if (rank < CAP) list[r * CAP + rank] = (unsigned)s | ((unsigned)d << 16);
    }
    __syncthreads();

    // flatten relations into 16-edge groups: entry = r<<16 | base<<8 | count
    if (threadIdx.x == 0) {
        int t = 0;
        for (int r = 0; r < N_REL; ++r) {
            int nr = min((int)cnt[r], CAP);
            for (int b = 0; b < nr; b += 16) {
                int c = min(16, nr - b);
                glist[t++] = ((unsigned)r << 16) | ((unsigned)b << 8) | (unsigned)c;
            }
        }
        ng_s = t;
    }
    __syncthreads();
    int ng = ng_s;

    int lane = threadIdx.x & 63;
    int wid  = threadIdx.x >> 6;
    int n16  = lane & 15;
    int quad = lane >> 4;
    float loss = 0.0f;

    // software-pipelined group loop (each wave: groups wid, wid+4, ...)
    int gi = wid;
    unsigned ge = 0;
    uint4 S = {0, 0, 0, 0}, D = {0, 0, 0, 0};
    if (gi < ng) {
        ge = glist[gi];
        int r = ge >> 16, b = (ge >> 8) & 255, c = ge & 255;
        unsigned rec = list[r * CAP + b + min(n16, c - 1)];
        S = *(const uint4*)(AS8 + ((size_t)(rec & 0xFFFF) << 6) + quad * 16);
        D = *(const uint4*)(AS8 + ((size_t)(rec >> 16) << 6) + quad * 16);
    }
    while (gi < ng) {
        int giN = gi + 4;
        unsigned geN = 0;
        uint4 SN = {0, 0, 0, 0}, DN = {0, 0, 0, 0};
        if (giN < ng) {
            geN = glist[giN];
            int rN = geN >> 16, bN = (geN >> 8) & 255, cN = geN & 255;
            unsigned recN = list[rN * CAP + bN + min(n16, cN - 1)];
            SN = *(const uint4*)(AS8 + ((size_t)(recN & 0xFFFF) << 6) + quad * 16);
            DN = *(const uint4*)(AS8 + ((size_t)(recN >> 16) << 6) + quad * 16);
        }

        int r = ge >> 16, c = ge & 255;
        long long bD0 = pack64(D.x, D.y);   // c=0 slots (first K=32)
        long long bD1 = pack64(D.z, D.w);   // c=1 slots
        floatx4 ac[4];
        #pragma unroll
        for (int mt = 0; mt < 4; ++mt) {
            uint4 wf = *(const uint4*)(Wp8 + ((r * 64 + mt * 16 + n16) << 6) + quad * 16);
            floatx4 z = {0.0f, 0.0f, 0.0f, 0.0f};
            z = __builtin_amdgcn_mfma_f32_16x16x32_fp8_fp8(pack64(wf.x, wf.y), bD0, z, 0, 0, 0);
            ac[mt] = __builtin_amdgcn_mfma_f32_16x16x32_fp8_fp8(pack64(wf.z, wf.w), bD1, z, 0, 0, 0);
        }
        // lane holds P[m = mt*16 + quad*4 + reg][n16]; S dword mt = those m's
        unsigned sw[4] = {S.x, S.y, S.z, S.w};
        float dot = 0.0f;
        #pragma unroll
        for (int mt = 0; mt < 4; ++mt) {
            floatx2 lo = __builtin_amdgcn_cvt_pk_f32_fp8((int)sw[mt], false);
            floatx2 hi = __builtin_amdgcn_cvt_pk_f32_fp8((int)sw[mt], true);
            dot = fmaf(lo.x, ac[mt][0], dot);
            dot = fmaf(lo.y, ac[mt][1], dot);
            dot = fmaf(hi.x, ac[mt][2], dot);
            dot = fmaf(hi.y, ac[mt][3], dot);
        }
        dot += __shfl_xor(dot, 16);
        dot += __shfl_xor(dot, 32);
        if (quad == 0 && n16 < c) {
            float x = sign * (dot + absent_bias[r]);
            loss += fmaxf(x, 0.0f) + __logf(1.0f + __expf(-fabsf(x)));
        }

        gi = giN; ge = geN; S = SN; D = DN;
    }

    loss += __shfl_xor(loss, 1);
    loss += __shfl_xor(loss, 2);
    loss += __shfl_xor(loss, 4);
    loss += __shfl_xor(loss, 8);
    loss += __shfl_xor(loss, 16);
    loss += __shfl_xor(loss, 32);
    if (lane == 0) red[wid] = loss;
    __syncthreads();
    if (threadIdx.x == 0)
        atomicAdd(out, (red[0] + red[1] + red[2] + red[3]) * (1.0f / (float)E_EDGES));
}

extern "C" void kernel_launch(void* const* d_in, const int* in_sizes, int n_in,
                              void* d_out, int out_size, void* d_ws, size_t ws_size,
                              hipStream_t stream) {
    const float* assign = (const float*)d_in[0];
    const float* icl    = (const float*)d_in[1];
    const float* la     = (const float*)d_in[2];
    const float* ab     = (const float*)d_in[3];
    const int*   ei     = (const int*)d_in[4];
    const int*   et     = (const int*)d_in[5];
    const int*   nei    = (const int*)d_in[6];
    const int*   net    = (const int*)d_in[7];
    float* out = (float*)d_out;

    // workspace: Wp8 32KB (pad 64KB) | AS8 3.2MB
    char* basep = (char*)d_ws;
    unsigned char* Wp8 = (unsigned char*)basep;
    unsigned char* AS8 = (unsigned char*)(basep + 65536);

    prep_kernel<<<256, 256, 0, stream>>>(assign, icl, la, Wp8, AS8, out);
    edge_kernel<<<2 * NBLK, 256, 0, stream>>>(AS8, Wp8, ab, ei, et, nei, net, out);
}

// Round 15
// 141.618 us; speedup vs baseline: 1.1462x; 1.1462x over previous
//
#include <hip/hip_runtime.h>
#include <hip/hip_bf16.h>
#include <math.h>

#define E_EDGES 1000000
#define N_NODES 50000
#define N_C     64
#define N_REL   8
#define CHB     1024        // edges per block
#define CAP     224         // per-rel LDS capacity (mean 128, sigma 10.6 -> 9 sigma)
#define NBLK    977         // ceil(1e6 / 1024)

typedef __attribute__((ext_vector_type(4))) float floatx4;
typedef __attribute__((ext_vector_type(2))) float floatx2;

// pack 4 fp32 -> 4 fp8 e4m3 (RNE); byte j = element j
static __device__ __forceinline__ unsigned pk4_fp8(float a, float b, float c, float d) {
    unsigned w = 0;
    w = __builtin_amdgcn_cvt_pk_fp8_f32(a, b, w, false);
    w = __builtin_amdgcn_cvt_pk_fp8_f32(c, d, w, true);
    return w;
}

static __device__ __forceinline__ long long pack64(unsigned lo, unsigned hi) {
    uint2 u; u.x = lo; u.y = hi;
    return __builtin_bit_cast(long long, u);
}

// kappa slot permutation (verified R11/R12): Wp8 byte (q*16 + c*8 + j) of row
// holds fp8(W[row][(2c+(j>>2))*16 + 4q + (j&3)]); AS8 row byte q*16+u holds
// elem (u>>2)*16 + 4q + (u&3). One b128 per lane serves both the MFMA B-op
// and the src dot.
__global__ __launch_bounds__(256) void prep_kernel(
    const float* __restrict__ assign,
    const float* __restrict__ icl,
    const float* __restrict__ la,
    unsigned char* __restrict__ Wp8,
    unsigned char* __restrict__ AS8,
    float* __restrict__ out)
{
    int tid = blockIdx.x * blockDim.x + threadIdx.x;
    int nth = gridDim.x * blockDim.x;
    if (tid == 0) out[0] = 0.0f;

    // Wp8: one thread per output dword (512 rows x 16 dwords)
    for (int idx = tid; idx < N_REL * N_C * 16; idx += nth) {
        int row = idx >> 4, dq = idx & 15;
        int q = dq >> 2, c = (dq >> 1) & 1, jh = dq & 1;
        int k0 = (2 * c + jh) * 16 + 4 * q;   // bytes b=0..3 -> k = k0 + b
        float wv[4];
        #pragma unroll
        for (int b = 0; b < 4; ++b) {
            int srci = (row << 6) + k0 + b;
            float w = 1.0f / (1.0f + __expf(-icl[srci]));
            float g = 1.0f / (1.0f + __expf(-la[srci])) * 1.2f - 0.1f;
            g = fminf(fmaxf(g, 0.0f), 1.0f);
            wv[b] = w * g;
        }
        ((unsigned*)Wp8)[idx] = pk4_fp8(wv[0], wv[1], wv[2], wv[3]);
    }

    // AS8: one thread per node row; dword[q*4 + mt] = elems [16mt+4q, +4)
    for (int n = tid; n < N_NODES; n += nth) {
        const float4* a4 = (const float4*)(assign + (size_t)n * N_C);
        unsigned w[16];
        #pragma unroll
        for (int i = 0; i < 16; ++i) {
            float4 v = a4[i];
            w[i] = pk4_fp8(v.x, v.y, v.z, v.w);   // w[i] = elems 4i..4i+3
        }
        uint4* as = (uint4*)(AS8 + (size_t)n * N_C);
        #pragma unroll
        for (int q = 0; q < 4; ++q) {
            uint4 o;
            o.x = w[0 * 4 + q];
            o.y = w[1 * 4 + q];
            o.z = w[2 * 4 + q];
            o.w = w[3 * 4 + q];
            as[q] = o;
        }
    }
}

// Fused edge pass (R12 structure): bin CHB edges by relation in LDS, then per
// relation MFMA-batch 16 edges/wave with native fp8 MFMA and stationary W
// fragments. NEW vs R12: prefetch the wave's next group's S/D gathers while
// computing the current group (W stays in registers; no other changes).
__global__ __launch_bounds__(256, 8) void edge_kernel(
    const unsigned char* __restrict__ AS8,
    const unsigned char* __restrict__ Wp8,
    const float* __restrict__ absent_bias,
    const int* __restrict__ ei, const int* __restrict__ et,
    const int* __restrict__ nei, const int* __restrict__ net,
    float* __restrict__ out)
{
    __shared__ unsigned list[N_REL * CAP];
    __shared__ unsigned cnt[N_REL];
    __shared__ float red[4];
    if (threadIdx.x < N_REL) cnt[threadIdx.x] = 0u;
    __syncthreads();

    int blk = blockIdx.x;
    bool isneg = blk >= NBLK;
    int lb = isneg ? blk - NBLK : blk;
    const int* Es = isneg ? nei : ei;
    const int* Et = isneg ? net : et;
    float sign = isneg ? 1.0f : -1.0f;
    int base = lb * CHB;
    int elim = min(base + CHB, E_EDGES);

    for (int e = base + threadIdx.x; e < elim; e += 256) {
        int s = Es[e];
        int d = Es[E_EDGES + e];
        int r = Et[e];
        unsigned rank = atomicAdd(&cnt[r], 1u);
        if (rank < CAP) list[r * CAP + rank] = (unsigned)s | ((unsigned)d << 16);
    }
    __syncthreads();

    int lane = threadIdx.x & 63;
    int wid  = threadIdx.x >> 6;
    int n16  = lane & 15;
    int quad = lane >> 4;
    float loss = 0.0f;

    for (int r = 0; r < N_REL; ++r) {
        int n_r = min((int)cnt[r], CAP);
        if (n_r == 0) continue;
        float bias = absent_bias[r];
        // stationary fp8 A-operand: one b128 per mt row-tile (kept in VGPRs)
        uint4 wfm[4];
        #pragma unroll
        for (int mt = 0; mt < 4; ++mt)
            wfm[mt] = *(const uint4*)(Wp8 + ((r * 64 + mt * 16 + n16) << 6) + quad * 16);

        // pipelined group loop: prefetch next group's S/D during compute
        int g = wid;
        bool valid = false;
        uint4 S = {0, 0, 0, 0}, D = {0, 0, 0, 0};
        if (g * 16 < n_r) {
            int idx = g * 16 + n16;
            valid = idx < n_r;
            unsigned rec = list[r * CAP + (valid ? idx : 0)];
            S = *(const uint4*)(AS8 + ((size_t)(rec & 0xFFFF) << 6) + quad * 16);
            D = *(const uint4*)(AS8 + ((size_t)(rec >> 16) << 6) + quad * 16);
        }
        while (g * 16 < n_r) {
            int g2 = g + 4;
            bool valid2 = false;
            uint4 S2 = {0, 0, 0, 0}, D2 = {0, 0, 0, 0};
            if (g2 * 16 < n_r) {
                int idx2 = g2 * 16 + n16;
                valid2 = idx2 < n_r;
                unsigned rec2 = list[r * CAP + (valid2 ? idx2 : 0)];
                S2 = *(const uint4*)(AS8 + ((size_t)(rec2 & 0xFFFF) << 6) + quad * 16);
                D2 = *(const uint4*)(AS8 + ((size_t)(rec2 >> 16) << 6) + quad * 16);
            }

            long long bD0 = pack64(D.x, D.y);   // c=0 slots (first K=32)
            long long bD1 = pack64(D.z, D.w);   // c=1 slots
            floatx4 ac[4];
            #pragma unroll
            for (int mt = 0; mt < 4; ++mt) {
                floatx4 z = {0.0f, 0.0f, 0.0f, 0.0f};
                z = __builtin_amdgcn_mfma_f32_16x16x32_fp8_fp8(
                        pack64(wfm[mt].x, wfm[mt].y), bD0, z, 0, 0, 0);
                ac[mt] = __builtin_amdgcn_mfma_f32_16x16x32_fp8_fp8(
                        pack64(wfm[mt].z, wfm[mt].w), bD1, z, 0, 0, 0);
            }
            // lane holds P[m = mt*16 + quad*4 + reg][n16]; S dword mt = those m's
            unsigned sw[4] = {S.x, S.y, S.z, S.w};
            float d0 = 0.0f, d1 = 0.0f;
            #pragma unroll
            for (int mt = 0; mt < 4; mt += 2) {
                floatx2 lo0 = __builtin_amdgcn_cvt_pk_f32_fp8((int)sw[mt], false);
                floatx2 hi0 = __builtin_amdgcn_cvt_pk_f32_fp8((int)sw[mt], true);
                floatx2 lo1 = __builtin_amdgcn_cvt_pk_f32_fp8((int)sw[mt + 1], false);
                floatx2 hi1 = __builtin_amdgcn_cvt_pk_f32_fp8((int)sw[mt + 1], true);
                d0 = fmaf(lo0.x, ac[mt][0], d0);
                d1 = fmaf(lo1.x, ac[mt + 1][0], d1);
                d0 = fmaf(lo0.y, ac[mt][1], d0);
                d1 = fmaf(lo1.y, ac[mt + 1][1], d1);
                d0 = fmaf(hi0.x, ac[mt][2], d0);
                d1 = fmaf(hi1.x, ac[mt + 1][2], d1);
                d0 = fmaf(hi0.y, ac[mt][3], d0);
                d1 = fmaf(hi1.y, ac[mt + 1][3], d1);
            }
            float dot = d0 + d1;
            dot += __shfl_xor(dot, 16);
            dot += __shfl_xor(dot, 32);
            if (quad == 0 && valid) {
                float x = sign * (dot + bias);
                loss += fmaxf(x, 0.0f) + __logf(1.0f + __expf(-fabsf(x)));
            }

            g = g2; valid = valid2; S = S2; D = D2;
        }
    }

    loss += __shfl_xor(loss, 1);
    loss += __shfl_xor(loss, 2);
    loss += __shfl_xor(loss, 4);
    loss += __shfl_xor(loss, 8);
    loss += __shfl_xor(loss, 16);
    loss += __shfl_xor(loss, 32);
    if (lane == 0) red[wid] = loss;
    __syncthreads();
    if (threadIdx.x == 0)
        atomicAdd(out, (red[0] + red[1] + red[2] + red[3]) * (1.0f / (float)E_EDGES));
}

extern "C" void kernel_launch(void* const* d_in, const int* in_sizes, int n_in,
                              void* d_out, int out_size, void* d_ws, size_t ws_size,
                              hipStream_t stream) {
    const float* assign = (const float*)d_in[0];
    const float* icl    = (const float*)d_in[1];
    const float* la     = (const float*)d_in[2];
    const float* ab     = (const float*)d_in[3];
    const int*   ei     = (const int*)d_in[4];
    const int*   et     = (const int*)d_in[5];
    const int*   nei    = (const int*)d_in[6];
    const int*   net    = (const int*)d_in[7];
    float* out = (float*)d_out;

    // workspace: Wp8 32KB (pad 64KB) | AS8 3.2MB
    char* basep = (char*)d_ws;
    unsigned char* Wp8 = (unsigned char*)basep;
    unsigned char* AS8 = (unsigned char*)(basep + 65536);

    prep_kernel<<<256, 256, 0, stream>>>(assign, icl, la, Wp8, AS8, out);
    edge_kernel<<<2 * NBLK, 256, 0, stream>>>(AS8, Wp8, ab, ei, et, nei, net, out);
}

// Round 16
// 135.445 us; speedup vs baseline: 1.1985x; 1.0456x over previous
//
#include <hip/hip_runtime.h>
#include <hip/hip_bf16.h>
#include <math.h>

#define E_EDGES 1000000
#define N_NODES 50000
#define N_C     64
#define N_REL   8
#define CHB     1024        // edges per block
#define CAP     224         // per-rel LDS capacity (mean 128, sigma 10.6 -> 9 sigma)
#define NBLK    977         // ceil(1e6 / 1024)

typedef __attribute__((ext_vector_type(4))) float floatx4;
typedef __attribute__((ext_vector_type(2))) float floatx2;

// pack 4 fp32 -> 4 fp8 e4m3 (RNE); byte j = element j
static __device__ __forceinline__ unsigned pk4_fp8(float a, float b, float c, float d) {
    unsigned w = 0;
    w = __builtin_amdgcn_cvt_pk_fp8_f32(a, b, w, false);
    w = __builtin_amdgcn_cvt_pk_fp8_f32(c, d, w, true);
    return w;
}

static __device__ __forceinline__ long long pack64(unsigned lo, unsigned hi) {
    uint2 u; u.x = lo; u.y = hi;
    return __builtin_bit_cast(long long, u);
}

// kappa slot permutation (verified R11/R12): Wp8 byte (q*16 + c*8 + j) of row
// holds fp8(W[row][(2c+(j>>2))*16 + 4q + (j&3)]); AS8 row byte q*16+u holds
// elem (u>>2)*16 + 4q + (u&3). One b128 per lane serves both the MFMA B-op
// and the src dot.
__global__ __launch_bounds__(256) void prep_kernel(
    const float* __restrict__ assign,
    const float* __restrict__ icl,
    const float* __restrict__ la,
    unsigned char* __restrict__ Wp8,
    unsigned char* __restrict__ AS8,
    float* __restrict__ out)
{
    int tid = blockIdx.x * blockDim.x + threadIdx.x;
    int nth = gridDim.x * blockDim.x;
    if (tid == 0) out[0] = 0.0f;

    // Wp8: one thread per output dword (512 rows x 16 dwords)
    for (int idx = tid; idx < N_REL * N_C * 16; idx += nth) {
        int row = idx >> 4, dq = idx & 15;
        int q = dq >> 2, c = (dq >> 1) & 1, jh = dq & 1;
        int k0 = (2 * c + jh) * 16 + 4 * q;   // bytes b=0..3 -> k = k0 + b
        float wv[4];
        #pragma unroll
        for (int b = 0; b < 4; ++b) {
            int srci = (row << 6) + k0 + b;
            float w = 1.0f / (1.0f + __expf(-icl[srci]));
            float g = 1.0f / (1.0f + __expf(-la[srci])) * 1.2f - 0.1f;
            g = fminf(fmaxf(g, 0.0f), 1.0f);
            wv[b] = w * g;
        }
        ((unsigned*)Wp8)[idx] = pk4_fp8(wv[0], wv[1], wv[2], wv[3]);
    }

    // AS8: one thread per node row; dword[q*4 + mt] = elems [16mt+4q, +4)
    for (int n = tid; n < N_NODES; n += nth) {
        const float4* a4 = (const float4*)(assign + (size_t)n * N_C);
        unsigned w[16];
        #pragma unroll
        for (int i = 0; i < 16; ++i) {
            float4 v = a4[i];
            w[i] = pk4_fp8(v.x, v.y, v.z, v.w);   // w[i] = elems 4i..4i+3
        }
        uint4* as = (uint4*)(AS8 + (size_t)n * N_C);
        #pragma unroll
        for (int q = 0; q < 4; ++q) {
            uint4 o;
            o.x = w[0 * 4 + q];
            o.y = w[1 * 4 + q];
            o.z = w[2 * 4 + q];
            o.w = w[3 * 4 + q];
            as[q] = o;
        }
    }
}

// Fused edge pass (R12 structure + S/D prefetch). __launch_bounds__(256,6):
// 84-VGPR cap fits the prefetch live range (R15's (256,8)=64 cap spilled:
// WRITE_SIZE 61KB -> 9.8MB); measured occupancy was scheduler-limited at
// ~4.7 waves/SIMD anyway, so the lower cap costs nothing real.
__global__ __launch_bounds__(256, 6) void edge_kernel(
    const unsigned char* __restrict__ AS8,
    const unsigned char* __restrict__ Wp8,
    const float* __restrict__ absent_bias,
    const int* __restrict__ ei, const int* __restrict__ et,
    const int* __restrict__ nei, const int* __restrict__ net,
    float* __restrict__ out)
{
    __shared__ unsigned list[N_REL * CAP];
    __shared__ unsigned cnt[N_REL];
    __shared__ float red[4];
    if (threadIdx.x < N_REL) cnt[threadIdx.x] = 0u;
    __syncthreads();

    int blk = blockIdx.x;
    bool isneg = blk >= NBLK;
    int lb = isneg ? blk - NBLK : blk;
    const int* Es = isneg ? nei : ei;
    const int* Et = isneg ? net : et;
    float sign = isneg ? 1.0f : -1.0f;
    int base = lb * CHB;
    int elim = min(base + CHB, E_EDGES);

    for (int e = base + threadIdx.x; e < elim; e += 256) {
        int s = Es[e];
        int d = Es[E_EDGES + e];
        int r = Et[e];
        unsigned rank = atomicAdd(&cnt[r], 1u);
        if (rank < CAP) list[r * CAP + rank] = (unsigned)s | ((unsigned)d << 16);
    }
    __syncthreads();

    int lane = threadIdx.x & 63;
    int wid  = threadIdx.x >> 6;
    int n16  = lane & 15;
    int quad = lane >> 4;
    float loss = 0.0f;

    for (int r = 0; r < N_REL; ++r) {
        int n_r = min((int)cnt[r], CAP);
        if (n_r == 0) continue;
        float bias = absent_bias[r];
        // stationary fp8 A-operand: one b128 per mt row-tile (kept in VGPRs)
        uint4 wfm[4];
        #pragma unroll
        for (int mt = 0; mt < 4; ++mt)
            wfm[mt] = *(const uint4*)(Wp8 + ((r * 64 + mt * 16 + n16) << 6) + quad * 16);

        // pipelined group loop: prefetch next group's S/D during compute
        int g = wid;
        bool valid = false;
        uint4 S = {0, 0, 0, 0}, D = {0, 0, 0, 0};
        if (g * 16 < n_r) {
            int idx = g * 16 + n16;
            valid = idx < n_r;
            unsigned rec = list[r * CAP + (valid ? idx : 0)];
            S = *(const uint4*)(AS8 + ((size_t)(rec & 0xFFFF) << 6) + quad * 16);
            D = *(const uint4*)(AS8 + ((size_t)(rec >> 16) << 6) + quad * 16);
        }
        while (g * 16 < n_r) {
            int g2 = g + 4;
            bool valid2 = false;
            uint4 S2 = {0, 0, 0, 0}, D2 = {0, 0, 0, 0};
            if (g2 * 16 < n_r) {
                int idx2 = g2 * 16 + n16;
                valid2 = idx2 < n_r;
                unsigned rec2 = list[r * CAP + (valid2 ? idx2 : 0)];
                S2 = *(const uint4*)(AS8 + ((size_t)(rec2 & 0xFFFF) << 6) + quad * 16);
                D2 = *(const uint4*)(AS8 + ((size_t)(rec2 >> 16) << 6) + quad * 16);
            }

            long long bD0 = pack64(D.x, D.y);   // c=0 slots (first K=32)
            long long bD1 = pack64(D.z, D.w);   // c=1 slots
            floatx4 ac[4];
            #pragma unroll
            for (int mt = 0; mt < 4; ++mt) {
                floatx4 z = {0.0f, 0.0f, 0.0f, 0.0f};
                z = __builtin_amdgcn_mfma_f32_16x16x32_fp8_fp8(
                        pack64(wfm[mt].x, wfm[mt].y), bD0, z, 0, 0, 0);
                ac[mt] = __builtin_amdgcn_mfma_f32_16x16x32_fp8_fp8(
                        pack64(wfm[mt].z, wfm[mt].w), bD1, z, 0, 0, 0);
            }
            // lane holds P[m = mt*16 + quad*4 + reg][n16]; S dword mt = those m's
            unsigned sw[4] = {S.x, S.y, S.z, S.w};
            float d0 = 0.0f, d1 = 0.0f;
            #pragma unroll
            for (int mt = 0; mt < 4; mt += 2) {
                floatx2 lo0 = __builtin_amdgcn_cvt_pk_f32_fp8((int)sw[mt], false);
                floatx2 hi0 = __builtin_amdgcn_cvt_pk_f32_fp8((int)sw[mt], true);
                floatx2 lo1 = __builtin_amdgcn_cvt_pk_f32_fp8((int)sw[mt + 1], false);
                floatx2 hi1 = __builtin_amdgcn_cvt_pk_f32_fp8((int)sw[mt + 1], true);
                d0 = fmaf(lo0.x, ac[mt][0], d0);
                d1 = fmaf(lo1.x, ac[mt + 1][0], d1);
                d0 = fmaf(lo0.y, ac[mt][1], d0);
                d1 = fmaf(lo1.y, ac[mt + 1][1], d1);
                d0 = fmaf(hi0.x, ac[mt][2], d0);
                d1 = fmaf(hi1.x, ac[mt + 1][2], d1);
                d0 = fmaf(hi0.y, ac[mt][3], d0);
                d1 = fmaf(hi1.y, ac[mt + 1][3], d1);
            }
            float dot = d0 + d1;
            dot += __shfl_xor(dot, 16);
            dot += __shfl_xor(dot, 32);
            if (quad == 0 && valid) {
                float x = sign * (dot + bias);
                loss += fmaxf(x, 0.0f) + __logf(1.0f + __expf(-fabsf(x)));
            }

            g = g2; valid = valid2; S = S2; D = D2;
        }
    }

    loss += __shfl_xor(loss, 1);
    loss += __shfl_xor(loss, 2);
    loss += __shfl_xor(loss, 4);
    loss += __shfl_xor(loss, 8);
    loss += __shfl_xor(loss, 16);
    loss += __shfl_xor(loss, 32);
    if (lane == 0) red[wid] = loss;
    __syncthreads();
    if (threadIdx.x == 0)
        atomicAdd(out, (red[0] + red[1] + red[2] + red[3]) * (1.0f / (float)E_EDGES));
}

extern "C" void kernel_launch(void* const* d_in, const int* in_sizes, int n_in,
                              void* d_out, int out_size, void* d_ws, size_t ws_size,
                              hipStream_t stream) {
    const float* assign = (const float*)d_in[0];
    const float* icl    = (const float*)d_in[1];
    const float* la     = (const float*)d_in[2];
    const float* ab     = (const float*)d_in[3];
    const int*   ei     = (const int*)d_in[4];
    const int*   et     = (const int*)d_in[5];
    const int*   nei    = (const int*)d_in[6];
    const int*   net    = (const int*)d_in[7];
    float* out = (float*)d_out;

    // workspace: Wp8 32KB (pad 64KB) | AS8 3.2MB
    char* basep = (char*)d_ws;
    unsigned char* Wp8 = (unsigned char*)basep;
    unsigned char* AS8 = (unsigned char*)(basep + 65536);

    prep_kernel<<<256, 256, 0, stream>>>(assign, icl, la, Wp8, AS8, out);
    edge_kernel<<<2 * NBLK, 256, 0, stream>>>(AS8, Wp8, ab, ei, et, nei, net, out);
}

// Round 17
// 129.073 us; speedup vs baseline: 1.2576x; 1.0494x over previous
//
#include <hip/hip_runtime.h>
#include <hip/hip_bf16.h>
#include <math.h>

#define E_EDGES 1000000
#define N_NODES 50000
#define N_C     64
#define N_REL   8
#define CHB     2048        // edges per block (halve block count vs R16)
#define CAP     384         // per-rel LDS capacity (mean 256, sigma 15 -> 8.5 sigma)
#define NBLK    489         // ceil(1e6 / 2048)

typedef __attribute__((ext_vector_type(4))) float floatx4;
typedef __attribute__((ext_vector_type(2))) float floatx2;

// pack 4 fp32 -> 4 fp8 e4m3 (RNE); byte j = element j
static __device__ __forceinline__ unsigned pk4_fp8(float a, float b, float c, float d) {
    unsigned w = 0;
    w = __builtin_amdgcn_cvt_pk_fp8_f32(a, b, w, false);
    w = __builtin_amdgcn_cvt_pk_fp8_f32(c, d, w, true);
    return w;
}

static __device__ __forceinline__ long long pack64(unsigned lo, unsigned hi) {
    uint2 u; u.x = lo; u.y = hi;
    return __builtin_bit_cast(long long, u);
}

// kappa slot permutation (verified R11/R12): Wp8 byte (q*16 + c*8 + j) of row
// holds fp8(W[row][(2c+(j>>2))*16 + 4q + (j&3)]); AS8 row byte q*16+u holds
// elem (u>>2)*16 + 4q + (u&3). One b128 per lane serves both the MFMA B-op
// and the src dot.
__global__ __launch_bounds__(256) void prep_kernel(
    const float* __restrict__ assign,
    const float* __restrict__ icl,
    const float* __restrict__ la,
    unsigned char* __restrict__ Wp8,
    unsigned char* __restrict__ AS8,
    float* __restrict__ out)
{
    int tid = blockIdx.x * blockDim.x + threadIdx.x;
    int nth = gridDim.x * blockDim.x;
    if (tid == 0) out[0] = 0.0f;

    // Wp8: one thread per output dword (512 rows x 16 dwords)
    for (int idx = tid; idx < N_REL * N_C * 16; idx += nth) {
        int row = idx >> 4, dq = idx & 15;
        int q = dq >> 2, c = (dq >> 1) & 1, jh = dq & 1;
        int k0 = (2 * c + jh) * 16 + 4 * q;   // bytes b=0..3 -> k = k0 + b
        float wv[4];
        #pragma unroll
        for (int b = 0; b < 4; ++b) {
            int srci = (row << 6) + k0 + b;
            float w = 1.0f / (1.0f + __expf(-icl[srci]));
            float g = 1.0f / (1.0f + __expf(-la[srci])) * 1.2f - 0.1f;
            g = fminf(fmaxf(g, 0.0f), 1.0f);
            wv[b] = w * g;
        }
        ((unsigned*)Wp8)[idx] = pk4_fp8(wv[0], wv[1], wv[2], wv[3]);
    }

    // AS8: one thread per node row; dword[q*4 + mt] = elems [16mt+4q, +4)
    for (int n = tid; n < N_NODES; n += nth) {
        const float4* a4 = (const float4*)(assign + (size_t)n * N_C);
        unsigned w[16];
        #pragma unroll
        for (int i = 0; i < 16; ++i) {
            float4 v = a4[i];
            w[i] = pk4_fp8(v.x, v.y, v.z, v.w);   // w[i] = elems 4i..4i+3
        }
        uint4* as = (uint4*)(AS8 + (size_t)n * N_C);
        #pragma unroll
        for (int q = 0; q < 4; ++q) {
            uint4 o;
            o.x = w[0 * 4 + q];
            o.y = w[1 * 4 + q];
            o.z = w[2 * 4 + q];
            o.w = w[3 * 4 + q];
            as[q] = o;
        }
    }
}

// Fused edge pass (R16 structure, CHB 2048): bin edges by relation in LDS,
// then per relation MFMA-batch 16 edges/wave (native fp8 MFMA, stationary W),
// with S/D prefetch across the now ~4-deep per-relation group loop.
__global__ __launch_bounds__(256, 6) void edge_kernel(
    const unsigned char* __restrict__ AS8,
    const unsigned char* __restrict__ Wp8,
    const float* __restrict__ absent_bias,
    const int* __restrict__ ei, const int* __restrict__ et,
    const int* __restrict__ nei, const int* __restrict__ net,
    float* __restrict__ out)
{
    __shared__ unsigned list[N_REL * CAP];
    __shared__ unsigned cnt[N_REL];
    __shared__ float red[4];
    if (threadIdx.x < N_REL) cnt[threadIdx.x] = 0u;
    __syncthreads();

    int blk = blockIdx.x;
    bool isneg = blk >= NBLK;
    int lb = isneg ? blk - NBLK : blk;
    const int* Es = isneg ? nei : ei;
    const int* Et = isneg ? net : et;
    float sign = isneg ? 1.0f : -1.0f;
    int base = lb * CHB;
    int elim = min(base + CHB, E_EDGES);

    for (int e = base + threadIdx.x; e < elim; e += 256) {
        int s = Es[e];
        int d = Es[E_EDGES + e];
        int r = Et[e];
        unsigned rank = atomicAdd(&cnt[r], 1u);
        if (rank < CAP) list[r * CAP + rank] = (unsigned)s | ((unsigned)d << 16);
    }
    __syncthreads();

    int lane = threadIdx.x & 63;
    int wid  = threadIdx.x >> 6;
    int n16  = lane & 15;
    int quad = lane >> 4;
    float loss = 0.0f;

    for (int r = 0; r < N_REL; ++r) {
        int n_r = min((int)cnt[r], CAP);
        if (n_r == 0) continue;
        float bias = absent_bias[r];
        // stationary fp8 A-operand: one b128 per mt row-tile (kept in VGPRs)
        uint4 wfm[4];
        #pragma unroll
        for (int mt = 0; mt < 4; ++mt)
            wfm[mt] = *(const uint4*)(Wp8 + ((r * 64 + mt * 16 + n16) << 6) + quad * 16);

        // pipelined group loop: prefetch next group's S/D during compute
        int g = wid;
        bool valid = false;
        uint4 S = {0, 0, 0, 0}, D = {0, 0, 0, 0};
        if (g * 16 < n_r) {
            int idx = g * 16 + n16;
            valid = idx < n_r;
            unsigned rec = list[r * CAP + (valid ? idx : 0)];
            S = *(const uint4*)(AS8 + ((size_t)(rec & 0xFFFF) << 6) + quad * 16);
            D = *(const uint4*)(AS8 + ((size_t)(rec >> 16) << 6) + quad * 16);
        }
        while (g * 16 < n_r) {
            int g2 = g + 4;
            bool valid2 = false;
            uint4 S2 = {0, 0, 0, 0}, D2 = {0, 0, 0, 0};
            if (g2 * 16 < n_r) {
                int idx2 = g2 * 16 + n16;
                valid2 = idx2 < n_r;
                unsigned rec2 = list[r * CAP + (valid2 ? idx2 : 0)];
                S2 = *(const uint4*)(AS8 + ((size_t)(rec2 & 0xFFFF) << 6) + quad * 16);
                D2 = *(const uint4*)(AS8 + ((size_t)(rec2 >> 16) << 6) + quad * 16);
            }

            long long bD0 = pack64(D.x, D.y);   // c=0 slots (first K=32)
            long long bD1 = pack64(D.z, D.w);   // c=1 slots
            floatx4 ac[4];
            #pragma unroll
            for (int mt = 0; mt < 4; ++mt) {
                floatx4 z = {0.0f, 0.0f, 0.0f, 0.0f};
                z = __builtin_amdgcn_mfma_f32_16x16x32_fp8_fp8(
                        pack64(wfm[mt].x, wfm[mt].y), bD0, z, 0, 0, 0);
                ac[mt] = __builtin_amdgcn_mfma_f32_16x16x32_fp8_fp8(
                        pack64(wfm[mt].z, wfm[mt].w), bD1, z, 0, 0, 0);
            }
            // lane holds P[m = mt*16 + quad*4 + reg][n16]; S dword mt = those m's
            unsigned sw[4] = {S.x, S.y, S.z, S.w};
            float d0 = 0.0f, d1 = 0.0f;
            #pragma unroll
            for (int mt = 0; mt < 4; mt += 2) {
                floatx2 lo0 = __builtin_amdgcn_cvt_pk_f32_fp8((int)sw[mt], false);
                floatx2 hi0 = __builtin_amdgcn_cvt_pk_f32_fp8((int)sw[mt], true);
                floatx2 lo1 = __builtin_amdgcn_cvt_pk_f32_fp8((int)sw[mt + 1], false);
                floatx2 hi1 = __builtin_amdgcn_cvt_pk_f32_fp8((int)sw[mt + 1], true);
                d0 = fmaf(lo0.x, ac[mt][0], d0);
                d1 = fmaf(lo1.x, ac[mt + 1][0], d1);
                d0 = fmaf(lo0.y, ac[mt][1], d0);
                d1 = fmaf(lo1.y, ac[mt + 1][1], d1);
                d0 = fmaf(hi0.x, ac[mt][2], d0);
                d1 = fmaf(hi1.x, ac[mt + 1][2], d1);
                d0 = fmaf(hi0.y, ac[mt][3], d0);
                d1 = fmaf(hi1.y, ac[mt + 1][3], d1);
            }
            float dot = d0 + d1;
            dot += __shfl_xor(dot, 16);
            dot += __shfl_xor(dot, 32);
            if (quad == 0 && valid) {
                float x = sign * (dot + bias);
                loss += fmaxf(x, 0.0f) + __logf(1.0f + __expf(-fabsf(x)));
            }

            g = g2; valid = valid2; S = S2; D = D2;
        }
    }

    loss += __shfl_xor(loss, 1);
    loss += __shfl_xor(loss, 2);
    loss += __shfl_xor(loss, 4);
    loss += __shfl_xor(loss, 8);
    loss += __shfl_xor(loss, 16);
    loss += __shfl_xor(loss, 32);
    if (lane == 0) red[wid] = loss;
    __syncthreads();
    if (threadIdx.x == 0)
        atomicAdd(out, (red[0] + red[1] + red[2] + red[3]) * (1.0f / (float)E_EDGES));
}

extern "C" void kernel_launch(void* const* d_in, const int* in_sizes, int n_in,
                              void* d_out, int out_size, void* d_ws, size_t ws_size,
                              hipStream_t stream) {
    const float* assign = (const float*)d_in[0];
    const float* icl    = (const float*)d_in[1];
    const float* la     = (const float*)d_in[2];
    const float* ab     = (const float*)d_in[3];
    const int*   ei     = (const int*)d_in[4];
    const int*   et     = (const int*)d_in[5];
    const int*   nei    = (const int*)d_in[6];
    const int*   net    = (const int*)d_in[7];
    float* out = (float*)d_out;

    // workspace: Wp8 32KB (pad 64KB) | AS8 3.2MB
    char* basep = (char*)d_ws;
    unsigned char* Wp8 = (unsigned char*)basep;
    unsigned char* AS8 = (unsigned char*)(basep + 65536);

    prep_kernel<<<256, 256, 0, stream>>>(assign, icl, la, Wp8, AS8, out);
    edge_kernel<<<2 * NBLK, 256, 0, stream>>>(AS8, Wp8, ab, ei, et, nei, net, out);
}